// Round 1
// baseline (658.894 us; speedup 1.0000x reference)
//
#include <hip/hip_runtime.h>
#include <hip/hip_bf16.h>

#define BATCH 2048
#define TT 2
#define NZ 100
#define SS 6
#define HH 64

// ---------------------------------------------------------------------------
// Actor: grid (32, 100), block 256.  blockIdx.y = zone n, blockIdx.x*64 = b0.
// thread: j = tid&63 (channel), bq = tid>>6 (16-batch subgroup).
// LDS (floats):
//   sWhh 12288 (rotated), sW1 4096 (rot), sW2 4096 (rot), sWih 1152,
//   sBih 192, sBhh 192, sB1 64, sB2 64, sW3 64, sB3 1, pad 3,
//   xT 768 ([t*6+s][64]), hT/aT/m1T/m2T 4x 64x68 (stride-68 transposes)
// total 40388 floats = 161552 B  (dynamic LDS, needs opt-in attribute)
// ---------------------------------------------------------------------------
__global__ __launch_bounds__(256, 1)
void actor_kernel(const float* __restrict__ x, const float* __restrict__ Wih,
                  const float* __restrict__ Whh, const float* __restrict__ bih,
                  const float* __restrict__ bhh, const float* __restrict__ W1,
                  const float* __restrict__ b1, const float* __restrict__ W2,
                  const float* __restrict__ b2, const float* __restrict__ W3,
                  const float* __restrict__ b3, float* __restrict__ p_flat)
{
    extern __shared__ float sm[];
    float* sWhh = sm;                 // 12288
    float* sW1  = sm + 12288;         // 4096
    float* sW2  = sm + 16384;         // 4096
    float* sWih = sm + 20480;         // 1152
    float* sBih = sm + 21632;         // 192
    float* sBhh = sm + 21824;         // 192
    float* sB1  = sm + 22016;         // 64
    float* sB2  = sm + 22080;         // 64
    float* sW3  = sm + 22144;         // 64
    float* sB3  = sm + 22208;         // 1 (+3 pad)
    float* xT   = sm + 22212;         // 768
    float* hT   = sm + 22980;         // 4352
    float* aT   = sm + 27332;         // 4352
    float* m1T  = sm + 31684;         // 4352
    float* m2T  = sm + 36036;         // 4352 -> ends 40388

    const int tid = threadIdx.x;
    const int n   = blockIdx.y;
    const int b0  = blockIdx.x * 64;
    const int j   = tid & 63;
    const int bq  = tid >> 6;
    const int boff = bq * 16;

    // ---- stage weights (rotated rows for bank-conflict-free lane reads) ----
    {
        const float* g = Whh + n * 12288;
        for (int i = tid; i < 12288; i += 256) {
            int gg = i >> 6, k = i & 63;
            sWhh[(gg << 6) + ((k + gg) & 63)] = g[i];
        }
        const float* g1 = W1 + n * 4096;
        const float* g2 = W2 + n * 4096;
        for (int i = tid; i < 4096; i += 256) {
            int gg = i >> 6, k = i & 63;
            int p = (gg << 6) + ((k + gg) & 63);
            sW1[p] = g1[i];
            sW2[p] = g2[i];
        }
        const float* gih = Wih + n * 1152;
        for (int i = tid; i < 1152; i += 256) sWih[i] = gih[i];
        if (tid < 192) { sBih[tid] = bih[n * 192 + tid]; sBhh[tid] = bhh[n * 192 + tid]; }
        if (tid < 64)  { sB1[tid] = b1[n * 64 + tid]; sB2[tid] = b2[n * 64 + tid]; sW3[tid] = W3[n * 64 + tid]; }
        if (tid == 0)  sB3[0] = b3[n];
        for (int i = tid; i < 768; i += 256) {
            int bl = i & 63, ts = i >> 6;
            int t = ts / 6, s = ts - t * 6;
            xT[i] = x[((size_t)(b0 + bl) * 2 + t) * 600 + n * 6 + s];
        }
    }
    __syncthreads();

    const float bihr = sBih[j], bihz = sBih[j + 64], bihn = sBih[j + 128];
    const float bhhr = sBhh[j], bhhz = sBhh[j + 64], bhhn = sBhh[j + 128];
    const float cb1 = sB1[j], cb2 = sB2[j];

    float hreg[16];
#pragma unroll
    for (int u = 0; u < 16; ++u) hreg[u] = 0.f;

    for (int t = 0; t < 2; ++t) {
        // ---- gates: gx (+ gh at t=1) ----
        float ar[16], az[16], axn[16], ahn[16];
#pragma unroll
        for (int u = 0; u < 16; ++u) {
            ar[u] = bihr + bhhr; az[u] = bihz + bhhz; axn[u] = bihn; ahn[u] = bhhn;
        }
#pragma unroll
        for (int s = 0; s < 6; ++s) {
            float wr = sWih[j * 6 + s];
            float wz = sWih[(j + 64) * 6 + s];
            float wn = sWih[(j + 128) * 6 + s];
            const float* xp = &xT[(t * 6 + s) * 64 + boff];
#pragma unroll
            for (int u = 0; u < 4; ++u) {
                float4 xv = *(const float4*)(xp + 4 * u);
                ar[4*u+0] += wr * xv.x; ar[4*u+1] += wr * xv.y; ar[4*u+2] += wr * xv.z; ar[4*u+3] += wr * xv.w;
                az[4*u+0] += wz * xv.x; az[4*u+1] += wz * xv.y; az[4*u+2] += wz * xv.z; az[4*u+3] += wz * xv.w;
                axn[4*u+0] += wn * xv.x; axn[4*u+1] += wn * xv.y; axn[4*u+2] += wn * xv.z; axn[4*u+3] += wn * xv.w;
            }
        }
        if (t == 1) {
            for (int k = 0; k < 64; ++k) {
                int rot = (k + j) & 63;
                float wr = sWhh[(j << 6) + rot];
                float wz = sWhh[((j + 64) << 6) + rot];
                float wn = sWhh[((j + 128) << 6) + rot];
                const float* hp = &hT[k * 68 + boff];
#pragma unroll
                for (int u = 0; u < 4; ++u) {
                    float4 hv = *(const float4*)(hp + 4 * u);
                    ar[4*u+0] += wr * hv.x; ar[4*u+1] += wr * hv.y; ar[4*u+2] += wr * hv.z; ar[4*u+3] += wr * hv.w;
                    az[4*u+0] += wz * hv.x; az[4*u+1] += wz * hv.y; az[4*u+2] += wz * hv.z; az[4*u+3] += wz * hv.w;
                    ahn[4*u+0] += wn * hv.x; ahn[4*u+1] += wn * hv.y; ahn[4*u+2] += wn * hv.z; ahn[4*u+3] += wn * hv.w;
                }
            }
        }
        // ---- GRU cell ----
        float h2[16];
#pragma unroll
        for (int u = 0; u < 16; ++u) {
            float r  = 1.f / (1.f + expf(-ar[u]));
            float zg = 1.f / (1.f + expf(-az[u]));
            float nn = tanhf(axn[u] + r * ahn[u]);
            h2[u] = (1.f - zg) * nn + zg * hreg[u];
            hreg[u] = h2[u];
        }
        __syncthreads();   // all gh readers of hT done before overwrite
        {
            float* hw = &hT[j * 68 + boff];
            float* aw = &aT[j * 68 + boff];
#pragma unroll
            for (int u = 0; u < 4; ++u) {
                float4 hv; hv.x = h2[4*u]; hv.y = h2[4*u+1]; hv.z = h2[4*u+2]; hv.w = h2[4*u+3];
                *(float4*)(hw + 4 * u) = hv;
                float4 av; av.x = fmaxf(hv.x, 0.f); av.y = fmaxf(hv.y, 0.f);
                av.z = fmaxf(hv.z, 0.f); av.w = fmaxf(hv.w, 0.f);
                *(float4*)(aw + 4 * u) = av;
            }
        }
        __syncthreads();
        // ---- MLP layer 1 ----
        float am[16];
#pragma unroll
        for (int u = 0; u < 16; ++u) am[u] = cb1;
        for (int k = 0; k < 64; ++k) {
            float w = sW1[(j << 6) + ((k + j) & 63)];
            const float* ap = &aT[k * 68 + boff];
#pragma unroll
            for (int u = 0; u < 4; ++u) {
                float4 av = *(const float4*)(ap + 4 * u);
                am[4*u+0] += w * av.x; am[4*u+1] += w * av.y; am[4*u+2] += w * av.z; am[4*u+3] += w * av.w;
            }
        }
        {
            float* mw = &m1T[j * 68 + boff];
#pragma unroll
            for (int u = 0; u < 4; ++u) {
                float4 v; v.x = fmaxf(am[4*u], 0.f); v.y = fmaxf(am[4*u+1], 0.f);
                v.z = fmaxf(am[4*u+2], 0.f); v.w = fmaxf(am[4*u+3], 0.f);
                *(float4*)(mw + 4 * u) = v;
            }
        }
        __syncthreads();
        // ---- MLP layer 2 ----
        float am2[16];
#pragma unroll
        for (int u = 0; u < 16; ++u) am2[u] = cb2;
        for (int k = 0; k < 64; ++k) {
            float w = sW2[(j << 6) + ((k + j) & 63)];
            const float* ap = &m1T[k * 68 + boff];
#pragma unroll
            for (int u = 0; u < 4; ++u) {
                float4 av = *(const float4*)(ap + 4 * u);
                am2[4*u+0] += w * av.x; am2[4*u+1] += w * av.y; am2[4*u+2] += w * av.z; am2[4*u+3] += w * av.w;
            }
        }
        {
            float* mw = &m2T[j * 68 + boff];
#pragma unroll
            for (int u = 0; u < 4; ++u) {
                float4 v; v.x = fmaxf(am2[4*u], 0.f); v.y = fmaxf(am2[4*u+1], 0.f);
                v.z = fmaxf(am2[4*u+2], 0.f); v.w = fmaxf(am2[4*u+3], 0.f);
                *(float4*)(mw + 4 * u) = v;
            }
        }
        __syncthreads();
        // ---- head: p = 3*(sigmoid(W3 . m2 + b3) - 0.5), lanes 0..63 = batch rows ----
        if (tid < 64) {
            float p0 = 0.f, p1 = 0.f, p2 = 0.f, p3 = 0.f;
            for (int k = 0; k < 64; k += 4) {
                p0 += sW3[k]     * m2T[k * 68 + tid];
                p1 += sW3[k + 1] * m2T[(k + 1) * 68 + tid];
                p2 += sW3[k + 2] * m2T[(k + 2) * 68 + tid];
                p3 += sW3[k + 3] * m2T[(k + 3) * 68 + tid];
            }
            float pacc = sB3[0] + ((p0 + p1) + (p2 + p3));
            float val = 3.f * (1.f / (1.f + expf(-pacc)) - 0.5f);
            p_flat[n * 4096 + (b0 + tid) * 2 + t] = val;   // (n,b,t)-major
        }
        __syncthreads();
    }
}

// ---------------------------------------------------------------------------
// Critic + p-last gather: grid 512, block 256 = 4 waves, wave per batch row b.
// lane = channel j.  Only zone 99 contributes; neighbors {99,89,0,0,98}.
// p[b,t,n] = p_flat[b*200 + t*100 + n]  (flat reinterpretation).
// ---------------------------------------------------------------------------
__global__ __launch_bounds__(256, 2)
void critic_kernel(const float* __restrict__ x, const float* __restrict__ p_flat,
                   const float* __restrict__ lmW1, const float* __restrict__ lmb1,
                   const float* __restrict__ lmW2, const float* __restrict__ lmb2,
                   const float* __restrict__ lmW3, const float* __restrict__ lmb3,
                   const float* __restrict__ scWih, const float* __restrict__ scWhh,
                   const float* __restrict__ scbih, const float* __restrict__ scbhh,
                   const float* __restrict__ scW1, const float* __restrict__ scb1,
                   const float* __restrict__ scW2, const float* __restrict__ scb2,
                   const float* __restrict__ scW3, const float* __restrict__ scb3,
                   float* __restrict__ out)
{
    __shared__ float sxi[4][72];    // [wid][t*36+c]
    __shared__ float shh[4][68];
    __shared__ float sab[4][68];
    __shared__ float sc1[4][68];
    __shared__ float sf1[4][132];

    const int tid = threadIdx.x;
    const int wid = tid >> 6;
    const int lane = tid & 63;
    const int b = blockIdx.x * 4 + wid;

    // build xi
    for (int idx = lane; idx < 72; idx += 64) {
        int t = idx / 36, c = idx - t * 36;
        float v = 0.f;
        if (c < 35) {
            int g = c / 7, e = c - g * 7;
            int z = (g == 0) ? 99 : (g == 1) ? 89 : (g == 4) ? 98 : -1;
            if (z >= 0)
                v = (e < 6) ? x[((size_t)b * 2 + t) * 600 + z * 6 + e]
                            : p_flat[b * 200 + t * 100 + z];
        }
        sxi[wid][idx] = v;
    }
    __syncthreads();

    // cgx = xi @ Wih^T + bih (rows lane, lane+64, lane+128; both t)
    float cg00 = scbih[lane], cg01 = scbih[lane + 64], cg02 = scbih[lane + 128];
    float cg10 = cg00, cg11 = cg01, cg12 = cg02;
    for (int c = 0; c < 35; ++c) {
        float w0 = scWih[lane * 35 + c];
        float w1 = scWih[(lane + 64) * 35 + c];
        float w2 = scWih[(lane + 128) * 35 + c];
        float x0 = sxi[wid][c], x1 = sxi[wid][36 + c];
        cg00 += w0 * x0; cg01 += w1 * x0; cg02 += w2 * x0;
        cg10 += w0 * x1; cg11 += w1 * x1; cg12 += w2 * x1;
    }
    const float bhr = scbhh[lane], bhz = scbhh[lane + 64], bhn = scbhh[lane + 128];
    // t=0 (h=0)
    float r  = 1.f / (1.f + expf(-(cg00 + bhr)));
    float zg = 1.f / (1.f + expf(-(cg01 + bhz)));
    float nn = tanhf(cg02 + r * bhn);
    float hj = (1.f - zg) * nn;
    shh[wid][lane] = hj;
    __syncthreads();
    // t=1
    float ghr = bhr, ghz = bhz, ghn = bhn;
    for (int kc = 0; kc < 16; ++kc) {
        float4 wr = *(const float4*)&scWhh[lane * 64 + kc * 4];
        float4 wz = *(const float4*)&scWhh[(lane + 64) * 64 + kc * 4];
        float4 wn = *(const float4*)&scWhh[(lane + 128) * 64 + kc * 4];
        float4 hv = *(const float4*)&shh[wid][kc * 4];
        ghr += wr.x * hv.x + wr.y * hv.y + wr.z * hv.z + wr.w * hv.w;
        ghz += wz.x * hv.x + wz.y * hv.y + wz.z * hv.z + wz.w * hv.w;
        ghn += wn.x * hv.x + wn.y * hv.y + wn.z * hv.z + wn.w * hv.w;
    }
    r  = 1.f / (1.f + expf(-(cg10 + ghr)));
    zg = 1.f / (1.f + expf(-(cg11 + ghz)));
    nn = tanhf(cg12 + r * ghn);
    hj = (1.f - zg) * nn + zg * hj;
    sab[wid][lane] = fmaxf(hj, 0.f);
    __syncthreads();
    // sc MLP layer 1
    float acc = scb1[lane];
    for (int kc = 0; kc < 16; ++kc) {
        float4 w = *(const float4*)&scW1[lane * 64 + kc * 4];
        float4 a = *(const float4*)&sab[wid][kc * 4];
        acc += w.x * a.x + w.y * a.y + w.z * a.z + w.w * a.w;
    }
    sc1[wid][lane] = fmaxf(acc, 0.f);
    __syncthreads();
    // sc MLP layer 2 + W3 partial
    float acc2 = scb2[lane];
    for (int kc = 0; kc < 16; ++kc) {
        float4 w = *(const float4*)&scW2[lane * 64 + kc * 4];
        float4 a = *(const float4*)&sc1[wid][kc * 4];
        acc2 += w.x * a.x + w.y * a.y + w.z * a.z + w.w * a.w;
    }
    float qpart = scW3[lane] * fmaxf(acc2, 0.f);
    // localized module on xi[t=1]
    float f1a = lmb1[lane], f1c = lmb1[lane + 64];
    for (int c = 0; c < 35; ++c) {
        float xv = sxi[wid][36 + c];
        f1a += lmW1[lane * 35 + c] * xv;
        f1c += lmW1[(lane + 64) * 35 + c] * xv;
    }
    sf1[wid][lane] = fmaxf(f1a, 0.f);
    sf1[wid][lane + 64] = fmaxf(f1c, 0.f);
    __syncthreads();
    float f2a = lmb2[lane], f2c = lmb2[lane + 64];
    for (int kc = 0; kc < 32; ++kc) {
        float4 fv = *(const float4*)&sf1[wid][kc * 4];
        float4 wa = *(const float4*)&lmW2[lane * 128 + kc * 4];
        float4 wc = *(const float4*)&lmW2[(lane + 64) * 128 + kc * 4];
        f2a += wa.x * fv.x + wa.y * fv.y + wa.z * fv.z + wa.w * fv.w;
        f2c += wc.x * fv.x + wc.y * fv.y + wc.z * fv.z + wc.w * fv.w;
    }
    float fpart = lmW3[lane] * fmaxf(f2a, 0.f) + lmW3[lane + 64] * fmaxf(f2c, 0.f);

    float tot = qpart + fpart;
    for (int m = 32; m > 0; m >>= 1) tot += __shfl_xor(tot, m, 64);
    if (lane == 0) out[204800 + b] = tot + scb3[0] + lmb3[0];

    // p[:, -1] gather: out[b*100 + l] = p_flat[b*200 + 100 + l]
    for (int l = lane; l < 100; l += 64)
        out[b * 100 + l] = p_flat[b * 200 + 100 + l];
}

extern "C" void kernel_launch(void* const* d_in, const int* in_sizes, int n_in,
                              void* d_out, int out_size, void* d_ws, size_t ws_size,
                              hipStream_t stream) {
    const float* x     = (const float*)d_in[0];
    const float* aWih  = (const float*)d_in[1];
    const float* aWhh  = (const float*)d_in[2];
    const float* abih  = (const float*)d_in[3];
    const float* abhh  = (const float*)d_in[4];
    const float* aW1   = (const float*)d_in[5];
    const float* ab1   = (const float*)d_in[6];
    const float* aW2   = (const float*)d_in[7];
    const float* ab2   = (const float*)d_in[8];
    const float* aW3   = (const float*)d_in[9];
    const float* ab3   = (const float*)d_in[10];
    const float* lmW1  = (const float*)d_in[11];
    const float* lmb1  = (const float*)d_in[12];
    const float* lmW2  = (const float*)d_in[13];
    const float* lmb2  = (const float*)d_in[14];
    const float* lmW3  = (const float*)d_in[15];
    const float* lmb3  = (const float*)d_in[16];
    const float* scWih = (const float*)d_in[17];
    const float* scWhh = (const float*)d_in[18];
    const float* scbih = (const float*)d_in[19];
    const float* scbhh = (const float*)d_in[20];
    const float* scW1  = (const float*)d_in[21];
    const float* scb1  = (const float*)d_in[22];
    const float* scW2  = (const float*)d_in[23];
    const float* scb2  = (const float*)d_in[24];
    const float* scW3  = (const float*)d_in[25];
    const float* scb3  = (const float*)d_in[26];
    float* out = (float*)d_out;
    float* p_flat = (float*)d_ws;   // 409600 floats = 1.6 MB

    const int lds_bytes = 40388 * 4;
    hipFuncSetAttribute((const void*)actor_kernel,
                        hipFuncAttributeMaxDynamicSharedMemorySize, lds_bytes);

    actor_kernel<<<dim3(32, 100), 256, lds_bytes, stream>>>(
        x, aWih, aWhh, abih, abhh, aW1, ab1, aW2, ab2, aW3, ab3, p_flat);

    critic_kernel<<<dim3(512), 256, 0, stream>>>(
        x, p_flat, lmW1, lmb1, lmW2, lmb2, lmW3, lmb3,
        scWih, scWhh, scbih, scbhh, scW1, scb1, scW2, scb2, scW3, scb3, out);
}

// Round 2
// 331.708 us; speedup vs baseline: 1.9864x; 1.9864x over previous
//
#include <hip/hip_runtime.h>
#include <hip/hip_bf16.h>

typedef __attribute__((ext_vector_type(8))) short short8;
typedef __attribute__((ext_vector_type(4))) float f32x4;

// ---------------- LDS layout (bytes) ----------------
#define OFF_WHH 0        // 192 rows x 72 shorts (stride 144B) = 27648
#define OFF_W1  27648    // 64 x 72 = 9216
#define OFF_W2  36864    // 9216
#define OFF_WIH 46080    // 192 x 40 shorts (K=32 zero-padded) = 15360
#define OFF_X   61440    // [4 waves][2 t][16 b][40 shorts] = 10240
#define OFF_H   71680    // [4 waves][16 b][72 shorts] = 9216
#define OFF_ACT 80896    // 9216
#define OFF_M1  90112    // 9216
#define OFF_B   99328    // 580 floats = 2320
#define LDS_TOTAL 101648

__device__ __forceinline__ unsigned short f2bf(float f) {
    unsigned u = __float_as_uint(f);
    return (unsigned short)((u + 0x7FFFu + ((u >> 16) & 1u)) >> 16);  // RNE
}
__device__ __forceinline__ float sigf(float x) {
    return __builtin_amdgcn_rcpf(1.f + __builtin_amdgcn_exp2f(-1.4426950408889634f * x));
}
__device__ __forceinline__ float tanhfast(float y) {
    return 1.f - 2.f * __builtin_amdgcn_rcpf(1.f + __builtin_amdgcn_exp2f(2.8853900817779268f * y));
}

// ---------------------------------------------------------------------------
// Actor (MFMA bf16): grid (32, 100), block 256 = 4 waves.
// blockIdx.y = zone n, blockIdx.x*64 = batch base. Wave w owns batches
// b0+w*16..+15 (N-tile of 16). lane: bcol = l&15 (batch col), grp = l>>4.
// GEMMs D[ch][b] = W[ch][k] * Act[k][b]; A,B frags both read as [dim][K]
// row-major contiguous-8 -> intra-lane K permutation cancels.
// C/D: col=lane&15 (batch), row=(lane>>4)*4+reg (channel)  [m89-verified].
// After the single staging barrier, all activation LDS tiles are wave-private:
// no further __syncthreads.
// ---------------------------------------------------------------------------
__global__ __launch_bounds__(256, 1)
void actor_kernel(const float* __restrict__ x, const float* __restrict__ Wih,
                  const float* __restrict__ Whh, const float* __restrict__ bih,
                  const float* __restrict__ bhh, const float* __restrict__ W1,
                  const float* __restrict__ b1, const float* __restrict__ W2,
                  const float* __restrict__ b2, const float* __restrict__ W3,
                  const float* __restrict__ b3, float* __restrict__ p_flat)
{
    extern __shared__ char sm[];
    unsigned short* uWhh = (unsigned short*)(sm + OFF_WHH);
    unsigned short* uW1  = (unsigned short*)(sm + OFF_W1);
    unsigned short* uW2  = (unsigned short*)(sm + OFF_W2);
    unsigned short* uWih = (unsigned short*)(sm + OFF_WIH);
    unsigned short* uX   = (unsigned short*)(sm + OFF_X);
    float* fB = (float*)(sm + OFF_B);

    const int tid = threadIdx.x;
    const int n   = blockIdx.y;
    const int b0  = blockIdx.x * 64;
    const int w    = tid >> 6;
    const int l    = tid & 63;
    const int bcol = l & 15;
    const int grp  = l >> 4;

    // ---- stage weights f32 -> bf16 LDS ----
    {
        const float* g = Whh + n * 12288;
        for (int i = tid; i < 12288; i += 256)
            uWhh[(i >> 6) * 72 + (i & 63)] = f2bf(g[i]);
        const float* g1 = W1 + n * 4096;
        const float* g2 = W2 + n * 4096;
        for (int i = tid; i < 4096; i += 256) {
            int p = (i >> 6) * 72 + (i & 63);
            uW1[p] = f2bf(g1[i]);
            uW2[p] = f2bf(g2[i]);
        }
        const float* gih = Wih + n * 1152;
        for (int i = tid; i < 7680; i += 256) {       // [192][40] zero-padded K
            int row = i / 40, c = i - row * 40;
            uWih[i] = (c < 6) ? f2bf(gih[row * 6 + c]) : (unsigned short)0;
        }
        for (int i = tid; i < 5120; i += 256) {       // [w][t][b][40] zero-padded
            int c = i % 40; int rest = i / 40;
            int b = rest & 15; rest >>= 4;
            int t = rest & 1;  int wv = rest >> 1;
            uX[i] = (c < 6)
                ? f2bf(x[(size_t)(b0 + wv * 16 + b) * 1200 + t * 600 + n * 6 + c])
                : (unsigned short)0;
        }
        for (int i = tid; i < 192; i += 256) { fB[i] = bih[n * 192 + i]; fB[192 + i] = bhh[n * 192 + i]; }
        if (tid < 64) { fB[384 + tid] = b1[n * 64 + tid]; fB[448 + tid] = b2[n * 64 + tid]; fB[512 + tid] = W3[n * 64 + tid]; }
        if (tid == 0) fB[576] = b3[n];
    }
    __syncthreads();

    // ---- per-thread GRU bias registers (chs = mt*16 + grp*4 + r) ----
    float bR[16], bZ[16], bXN[16], bHN[16];
#pragma unroll
    for (int mt = 0; mt < 4; ++mt)
#pragma unroll
        for (int r = 0; r < 4; ++r) {
            int ch = mt * 16 + grp * 4 + r;
            bR[mt * 4 + r]  = fB[ch] + fB[192 + ch];
            bZ[mt * 4 + r]  = fB[64 + ch] + fB[256 + ch];
            bXN[mt * 4 + r] = fB[128 + ch];
            bHN[mt * 4 + r] = fB[320 + ch];
        }
    const float b3v = fB[576];

    const int arow = (l & 15);   // weight row within M-tile
    f32x4 hp[4];
#pragma unroll
    for (int mt = 0; mt < 4; ++mt) hp[mt] = (f32x4){0.f, 0.f, 0.f, 0.f};

#pragma unroll
    for (int t = 0; t < 2; ++t) {
        // ---- gate accumulators, bias-initialized ----
        f32x4 aR[4], aZ[4], aXN[4], aHN[4];
#pragma unroll
        for (int mt = 0; mt < 4; ++mt) {
            aR[mt]  = (f32x4){bR[mt*4+0],  bR[mt*4+1],  bR[mt*4+2],  bR[mt*4+3]};
            aZ[mt]  = (f32x4){bZ[mt*4+0],  bZ[mt*4+1],  bZ[mt*4+2],  bZ[mt*4+3]};
            aXN[mt] = (f32x4){bXN[mt*4+0], bXN[mt*4+1], bXN[mt*4+2], bXN[mt*4+3]};
            aHN[mt] = (f32x4){bHN[mt*4+0], bHN[mt*4+1], bHN[mt*4+2], bHN[mt*4+3]};
        }
        // ---- gx: A = Wih (K=32 padded), B = x ----
        {
            short8 bx = *(const short8*)(sm + OFF_X + w * 2560 + t * 1280 + bcol * 80 + grp * 16);
#pragma unroll
            for (int mt = 0; mt < 4; ++mt) {
                short8 a0 = *(const short8*)(sm + OFF_WIH + (0 + mt) * 1280 + arow * 80 + grp * 16);
                short8 a1 = *(const short8*)(sm + OFF_WIH + (4 + mt) * 1280 + arow * 80 + grp * 16);
                short8 a2 = *(const short8*)(sm + OFF_WIH + (8 + mt) * 1280 + arow * 80 + grp * 16);
                aR[mt]  = __builtin_amdgcn_mfma_f32_16x16x32_bf16(a0, bx, aR[mt], 0, 0, 0);
                aZ[mt]  = __builtin_amdgcn_mfma_f32_16x16x32_bf16(a1, bx, aZ[mt], 0, 0, 0);
                aXN[mt] = __builtin_amdgcn_mfma_f32_16x16x32_bf16(a2, bx, aXN[mt], 0, 0, 0);
            }
        }
        // ---- gh (t=1 only): A = Whh, B = h from LDS ----
        if (t == 1) {
            short8 bh0 = *(const short8*)(sm + OFF_H + w * 2304 + bcol * 144 + grp * 16);
            short8 bh1 = *(const short8*)(sm + OFF_H + w * 2304 + bcol * 144 + grp * 16 + 64);
#pragma unroll
            for (int mt = 0; mt < 4; ++mt) {
                short8 r0 = *(const short8*)(sm + OFF_WHH + (0 + mt) * 2304 + arow * 144 + grp * 16);
                short8 r1 = *(const short8*)(sm + OFF_WHH + (0 + mt) * 2304 + arow * 144 + grp * 16 + 64);
                aR[mt] = __builtin_amdgcn_mfma_f32_16x16x32_bf16(r0, bh0, aR[mt], 0, 0, 0);
                aR[mt] = __builtin_amdgcn_mfma_f32_16x16x32_bf16(r1, bh1, aR[mt], 0, 0, 0);
                short8 z0 = *(const short8*)(sm + OFF_WHH + (4 + mt) * 2304 + arow * 144 + grp * 16);
                short8 z1 = *(const short8*)(sm + OFF_WHH + (4 + mt) * 2304 + arow * 144 + grp * 16 + 64);
                aZ[mt] = __builtin_amdgcn_mfma_f32_16x16x32_bf16(z0, bh0, aZ[mt], 0, 0, 0);
                aZ[mt] = __builtin_amdgcn_mfma_f32_16x16x32_bf16(z1, bh1, aZ[mt], 0, 0, 0);
                short8 n0 = *(const short8*)(sm + OFF_WHH + (8 + mt) * 2304 + arow * 144 + grp * 16);
                short8 n1 = *(const short8*)(sm + OFF_WHH + (8 + mt) * 2304 + arow * 144 + grp * 16 + 64);
                aHN[mt] = __builtin_amdgcn_mfma_f32_16x16x32_bf16(n0, bh0, aHN[mt], 0, 0, 0);
                aHN[mt] = __builtin_amdgcn_mfma_f32_16x16x32_bf16(n1, bh1, aHN[mt], 0, 0, 0);
            }
        }
        // ---- GRU cell (fp32 regs) + write h (bf16) / relu(h) to LDS ----
#pragma unroll
        for (int mt = 0; mt < 4; ++mt) {
            f32x4 h2;
#pragma unroll
            for (int r = 0; r < 4; ++r) {
                float rg = sigf(aR[mt][r]);
                float zg = sigf(aZ[mt][r]);
                float nn = tanhfast(aXN[mt][r] + rg * aHN[mt][r]);
                h2[r] = nn + zg * (hp[mt][r] - nn);
            }
            hp[mt] = h2;
            unsigned short s0 = f2bf(h2[0]), s1 = f2bf(h2[1]), s2 = f2bf(h2[2]), s3 = f2bf(h2[3]);
            unsigned short a0 = f2bf(fmaxf(h2[0], 0.f)), a1 = f2bf(fmaxf(h2[1], 0.f));
            unsigned short a2 = f2bf(fmaxf(h2[2], 0.f)), a3 = f2bf(fmaxf(h2[3], 0.f));
            uint2 ph; ph.x = (unsigned)s0 | ((unsigned)s1 << 16); ph.y = (unsigned)s2 | ((unsigned)s3 << 16);
            uint2 pa; pa.x = (unsigned)a0 | ((unsigned)a1 << 16); pa.y = (unsigned)a2 | ((unsigned)a3 << 16);
            if (t == 0)
                *(uint2*)(sm + OFF_H + w * 2304 + bcol * 144 + mt * 32 + grp * 8) = ph;
            *(uint2*)(sm + OFF_ACT + w * 2304 + bcol * 144 + mt * 32 + grp * 8) = pa;
        }
        // ---- MLP layer 1: relu(W1 . act + b1) -> sM1 ----
        {
            short8 ba0 = *(const short8*)(sm + OFF_ACT + w * 2304 + bcol * 144 + grp * 16);
            short8 ba1 = *(const short8*)(sm + OFF_ACT + w * 2304 + bcol * 144 + grp * 16 + 64);
            f32x4 aM[4];
#pragma unroll
            for (int mt = 0; mt < 4; ++mt) {
                int ch = mt * 16 + grp * 4;
                aM[mt] = (f32x4){fB[384 + ch], fB[384 + ch + 1], fB[384 + ch + 2], fB[384 + ch + 3]};
                short8 a0 = *(const short8*)(sm + OFF_W1 + mt * 2304 + arow * 144 + grp * 16);
                short8 a1 = *(const short8*)(sm + OFF_W1 + mt * 2304 + arow * 144 + grp * 16 + 64);
                aM[mt] = __builtin_amdgcn_mfma_f32_16x16x32_bf16(a0, ba0, aM[mt], 0, 0, 0);
                aM[mt] = __builtin_amdgcn_mfma_f32_16x16x32_bf16(a1, ba1, aM[mt], 0, 0, 0);
            }
#pragma unroll
            for (int mt = 0; mt < 4; ++mt) {
                unsigned short m0 = f2bf(fmaxf(aM[mt][0], 0.f)), m1 = f2bf(fmaxf(aM[mt][1], 0.f));
                unsigned short m2 = f2bf(fmaxf(aM[mt][2], 0.f)), m3 = f2bf(fmaxf(aM[mt][3], 0.f));
                uint2 pm; pm.x = (unsigned)m0 | ((unsigned)m1 << 16); pm.y = (unsigned)m2 | ((unsigned)m3 << 16);
                *(uint2*)(sm + OFF_M1 + w * 2304 + bcol * 144 + mt * 32 + grp * 8) = pm;
            }
        }
        // ---- MLP layer 2 + head ----
        {
            short8 bm0 = *(const short8*)(sm + OFF_M1 + w * 2304 + bcol * 144 + grp * 16);
            short8 bm1 = *(const short8*)(sm + OFF_M1 + w * 2304 + bcol * 144 + grp * 16 + 64);
            f32x4 aM2[4];
#pragma unroll
            for (int mt = 0; mt < 4; ++mt) {
                int ch = mt * 16 + grp * 4;
                aM2[mt] = (f32x4){fB[448 + ch], fB[448 + ch + 1], fB[448 + ch + 2], fB[448 + ch + 3]};
                short8 a0 = *(const short8*)(sm + OFF_W2 + mt * 2304 + arow * 144 + grp * 16);
                short8 a1 = *(const short8*)(sm + OFF_W2 + mt * 2304 + arow * 144 + grp * 16 + 64);
                aM2[mt] = __builtin_amdgcn_mfma_f32_16x16x32_bf16(a0, bm0, aM2[mt], 0, 0, 0);
                aM2[mt] = __builtin_amdgcn_mfma_f32_16x16x32_bf16(a1, bm1, aM2[mt], 0, 0, 0);
            }
            float part = 0.f;
#pragma unroll
            for (int mt = 0; mt < 4; ++mt) {
                int ch = mt * 16 + grp * 4;
#pragma unroll
                for (int r = 0; r < 4; ++r)
                    part += fB[512 + ch + r] * fmaxf(aM2[mt][r], 0.f);
            }
            part += __shfl_xor(part, 16, 64);
            part += __shfl_xor(part, 32, 64);
            float val = 3.f * (sigf(part + b3v) - 0.5f);
            if (l < 16)
                p_flat[n * 4096 + (b0 + w * 16 + bcol) * 2 + t] = val;   // (n,b,t)-major
        }
    }
}

// ---------------------------------------------------------------------------
// Critic + p-last gather (unchanged from round 1): grid 512, block 256,
// wave per batch row. Only zone 99 contributes; neighbors {99,89,0,0,98}.
// ---------------------------------------------------------------------------
__global__ __launch_bounds__(256, 2)
void critic_kernel(const float* __restrict__ x, const float* __restrict__ p_flat,
                   const float* __restrict__ lmW1, const float* __restrict__ lmb1,
                   const float* __restrict__ lmW2, const float* __restrict__ lmb2,
                   const float* __restrict__ lmW3, const float* __restrict__ lmb3,
                   const float* __restrict__ scWih, const float* __restrict__ scWhh,
                   const float* __restrict__ scbih, const float* __restrict__ scbhh,
                   const float* __restrict__ scW1, const float* __restrict__ scb1,
                   const float* __restrict__ scW2, const float* __restrict__ scb2,
                   const float* __restrict__ scW3, const float* __restrict__ scb3,
                   float* __restrict__ out)
{
    __shared__ float sxi[4][72];
    __shared__ float shh[4][68];
    __shared__ float sab[4][68];
    __shared__ float sc1[4][68];
    __shared__ float sf1[4][132];

    const int tid = threadIdx.x;
    const int wid = tid >> 6;
    const int lane = tid & 63;
    const int b = blockIdx.x * 4 + wid;

    for (int idx = lane; idx < 72; idx += 64) {
        int t = idx / 36, c = idx - t * 36;
        float v = 0.f;
        if (c < 35) {
            int g = c / 7, e = c - g * 7;
            int z = (g == 0) ? 99 : (g == 1) ? 89 : (g == 4) ? 98 : -1;
            if (z >= 0)
                v = (e < 6) ? x[((size_t)b * 2 + t) * 600 + z * 6 + e]
                            : p_flat[b * 200 + t * 100 + z];
        }
        sxi[wid][idx] = v;
    }
    __syncthreads();

    float cg00 = scbih[lane], cg01 = scbih[lane + 64], cg02 = scbih[lane + 128];
    float cg10 = cg00, cg11 = cg01, cg12 = cg02;
    for (int c = 0; c < 35; ++c) {
        float w0 = scWih[lane * 35 + c];
        float w1 = scWih[(lane + 64) * 35 + c];
        float w2 = scWih[(lane + 128) * 35 + c];
        float x0 = sxi[wid][c], x1 = sxi[wid][36 + c];
        cg00 += w0 * x0; cg01 += w1 * x0; cg02 += w2 * x0;
        cg10 += w0 * x1; cg11 += w1 * x1; cg12 += w2 * x1;
    }
    const float bhr = scbhh[lane], bhz = scbhh[lane + 64], bhn = scbhh[lane + 128];
    float r  = 1.f / (1.f + expf(-(cg00 + bhr)));
    float zg = 1.f / (1.f + expf(-(cg01 + bhz)));
    float nn = tanhf(cg02 + r * bhn);
    float hj = (1.f - zg) * nn;
    shh[wid][lane] = hj;
    __syncthreads();
    float ghr = bhr, ghz = bhz, ghn = bhn;
    for (int kc = 0; kc < 16; ++kc) {
        float4 wr = *(const float4*)&scWhh[lane * 64 + kc * 4];
        float4 wz = *(const float4*)&scWhh[(lane + 64) * 64 + kc * 4];
        float4 wn = *(const float4*)&scWhh[(lane + 128) * 64 + kc * 4];
        float4 hv = *(const float4*)&shh[wid][kc * 4];
        ghr += wr.x * hv.x + wr.y * hv.y + wr.z * hv.z + wr.w * hv.w;
        ghz += wz.x * hv.x + wz.y * hv.y + wz.z * hv.z + wz.w * hv.w;
        ghn += wn.x * hv.x + wn.y * hv.y + wn.z * hv.z + wn.w * hv.w;
    }
    r  = 1.f / (1.f + expf(-(cg10 + ghr)));
    zg = 1.f / (1.f + expf(-(cg11 + ghz)));
    nn = tanhf(cg12 + r * ghn);
    hj = (1.f - zg) * nn + zg * hj;
    sab[wid][lane] = fmaxf(hj, 0.f);
    __syncthreads();
    float acc = scb1[lane];
    for (int kc = 0; kc < 16; ++kc) {
        float4 wv = *(const float4*)&scW1[lane * 64 + kc * 4];
        float4 av = *(const float4*)&sab[wid][kc * 4];
        acc += wv.x * av.x + wv.y * av.y + wv.z * av.z + wv.w * av.w;
    }
    sc1[wid][lane] = fmaxf(acc, 0.f);
    __syncthreads();
    float acc2 = scb2[lane];
    for (int kc = 0; kc < 16; ++kc) {
        float4 wv = *(const float4*)&scW2[lane * 64 + kc * 4];
        float4 av = *(const float4*)&sc1[wid][kc * 4];
        acc2 += wv.x * av.x + wv.y * av.y + wv.z * av.z + wv.w * av.w;
    }
    float qpart = scW3[lane] * fmaxf(acc2, 0.f);
    float f1a = lmb1[lane], f1c = lmb1[lane + 64];
    for (int c = 0; c < 35; ++c) {
        float xv = sxi[wid][36 + c];
        f1a += lmW1[lane * 35 + c] * xv;
        f1c += lmW1[(lane + 64) * 35 + c] * xv;
    }
    sf1[wid][lane] = fmaxf(f1a, 0.f);
    sf1[wid][lane + 64] = fmaxf(f1c, 0.f);
    __syncthreads();
    float f2a = lmb2[lane], f2c = lmb2[lane + 64];
    for (int kc = 0; kc < 32; ++kc) {
        float4 fv = *(const float4*)&sf1[wid][kc * 4];
        float4 wa = *(const float4*)&lmW2[lane * 128 + kc * 4];
        float4 wc = *(const float4*)&lmW2[(lane + 64) * 128 + kc * 4];
        f2a += wa.x * fv.x + wa.y * fv.y + wa.z * fv.z + wa.w * fv.w;
        f2c += wc.x * fv.x + wc.y * fv.y + wc.z * fv.z + wc.w * fv.w;
    }
    float fpart = lmW3[lane] * fmaxf(f2a, 0.f) + lmW3[lane + 64] * fmaxf(f2c, 0.f);

    float tot = qpart + fpart;
    for (int m = 32; m > 0; m >>= 1) tot += __shfl_xor(tot, m, 64);
    if (lane == 0) out[204800 + b] = tot + scb3[0] + lmb3[0];

    for (int l2 = lane; l2 < 100; l2 += 64)
        out[b * 100 + l2] = p_flat[b * 200 + 100 + l2];
}

extern "C" void kernel_launch(void* const* d_in, const int* in_sizes, int n_in,
                              void* d_out, int out_size, void* d_ws, size_t ws_size,
                              hipStream_t stream) {
    const float* x     = (const float*)d_in[0];
    const float* aWih  = (const float*)d_in[1];
    const float* aWhh  = (const float*)d_in[2];
    const float* abih  = (const float*)d_in[3];
    const float* abhh  = (const float*)d_in[4];
    const float* aW1   = (const float*)d_in[5];
    const float* ab1   = (const float*)d_in[6];
    const float* aW2   = (const float*)d_in[7];
    const float* ab2   = (const float*)d_in[8];
    const float* aW3   = (const float*)d_in[9];
    const float* ab3   = (const float*)d_in[10];
    const float* lmW1  = (const float*)d_in[11];
    const float* lmb1  = (const float*)d_in[12];
    const float* lmW2  = (const float*)d_in[13];
    const float* lmb2  = (const float*)d_in[14];
    const float* lmW3  = (const float*)d_in[15];
    const float* lmb3  = (const float*)d_in[16];
    const float* scWih = (const float*)d_in[17];
    const float* scWhh = (const float*)d_in[18];
    const float* scbih = (const float*)d_in[19];
    const float* scbhh = (const float*)d_in[20];
    const float* scW1  = (const float*)d_in[21];
    const float* scb1  = (const float*)d_in[22];
    const float* scW2  = (const float*)d_in[23];
    const float* scb2  = (const float*)d_in[24];
    const float* scW3  = (const float*)d_in[25];
    const float* scb3  = (const float*)d_in[26];
    float* out = (float*)d_out;
    float* p_flat = (float*)d_ws;   // 409600 floats = 1.6 MB

    hipFuncSetAttribute((const void*)actor_kernel,
                        hipFuncAttributeMaxDynamicSharedMemorySize, LDS_TOTAL);

    actor_kernel<<<dim3(32, 100), 256, LDS_TOTAL, stream>>>(
        x, aWih, aWhh, abih, abhh, aW1, ab1, aW2, ab2, aW3, ab3, p_flat);

    critic_kernel<<<dim3(512), 256, 0, stream>>>(
        x, p_flat, lmW1, lmb1, lmW2, lmb2, lmW3, lmb3,
        scWih, scWhh, scbih, scbhh, scW1, scb1, scW2, scb2, scW3, scb3, out);
}

// Round 3
// 171.825 us; speedup vs baseline: 3.8347x; 1.9305x over previous
//
#include <hip/hip_runtime.h>
#include <hip/hip_bf16.h>

typedef __attribute__((ext_vector_type(8))) short short8;
typedef __attribute__((ext_vector_type(4))) float f32x4;

// ---- ws layout: p_flat (409600 f32 = 1638400 B) then bf16 weight slabs ----
// per zone (shorts): Wih [192][32] @0, Whh [192][64] @6144,
//                    W1 [64][64] @18432, W2 [64][64] @22528; stride 26624.
#define ZW 26624
#define WS_W_OFF_BYTES 1638400

// ---- actor LDS (bytes) ----
#define OFF_X   0        // [4w][2t][16b][8k] shorts = 2048
#define OFF_H   2048     // [4w][16b][72] shorts = 9216
#define OFF_ACT 11264    // [4w][16b][72] shorts = 9216 (ACT, then overwritten by M1)
#define OFF_B   20480    // 577 floats = 2308
#define LDS_TOTAL 22800

__device__ __forceinline__ unsigned short f2bf(float f) {
    unsigned u = __float_as_uint(f);
    return (unsigned short)((u + 0x7FFFu + ((u >> 16) & 1u)) >> 16);  // RNE
}
__device__ __forceinline__ float sigf(float x) {
    return __builtin_amdgcn_rcpf(1.f + __builtin_amdgcn_exp2f(-1.4426950408889634f * x));
}
__device__ __forceinline__ float tanhfast(float y) {
    return 1.f - 2.f * __builtin_amdgcn_rcpf(1.f + __builtin_amdgcn_exp2f(2.8853900817779268f * y));
}

// ---------------------------------------------------------------------------
// Pre-pass: convert actor weights f32 -> bf16 fragment-ready slabs in ws.
// ---------------------------------------------------------------------------
__global__ __launch_bounds__(256)
void convert_kernel(const float* __restrict__ Wih, const float* __restrict__ Whh,
                    const float* __restrict__ W1, const float* __restrict__ W2,
                    unsigned short* __restrict__ dst)
{
    int idx = blockIdx.x * 256 + threadIdx.x;
    if (idx >= 100 * ZW) return;
    int n = idx / ZW;
    int i = idx - n * ZW;
    float v;
    if (i < 6144) {
        int row = i >> 5, k = i & 31;
        v = (k < 6) ? Wih[n * 1152 + row * 6 + k] : 0.f;
    } else if (i < 18432) {
        int j = i - 6144;
        v = Whh[n * 12288 + (j >> 6) * 64 + (j & 63)];
    } else if (i < 22528) {
        int j = i - 18432;
        v = W1[n * 4096 + (j >> 6) * 64 + (j & 63)];
    } else {
        int j = i - 22528;
        v = W2[n * 4096 + (j >> 6) * 64 + (j & 63)];
    }
    dst[idx] = f2bf(v);
}

// ---------------------------------------------------------------------------
// Actor (MFMA bf16, weights from global/L2): grid (32,100), block 256 = 4 waves.
// Wave w owns batches b0+w*16..+15. lane: bcol/arow = l&15, grp = l>>4.
// A-frag: lane reads W[row = tile*16 + (l&15)][k = grp*8 .. +7] (16B global).
// B-frag: lane reads Act[bcol][k = grp*8..+7] from per-wave LDS.
// C/D: col=lane&15 (batch), row=(lane>>4)*4+reg (channel)  [m89-verified].
// Only one __syncthreads (x/bias staging); activations are wave-private.
// ---------------------------------------------------------------------------
__global__ __launch_bounds__(256, 4)
void actor_kernel(const float* __restrict__ x, const unsigned short* __restrict__ wz,
                  const float* __restrict__ bih, const float* __restrict__ bhh,
                  const float* __restrict__ b1, const float* __restrict__ b2,
                  const float* __restrict__ W3, const float* __restrict__ b3,
                  float* __restrict__ p_flat)
{
    extern __shared__ char sm[];
    unsigned short* uX = (unsigned short*)(sm + OFF_X);
    float* fB = (float*)(sm + OFF_B);

    const int tid = threadIdx.x;
    const int n   = blockIdx.y;
    const int b0  = blockIdx.x * 64;
    const int w    = tid >> 6;
    const int l    = tid & 63;
    const int bcol = l & 15;
    const int grp  = l >> 4;
    const unsigned short* zb = wz + (size_t)n * ZW;

    // ---- stage x (bf16, K=8 padded) + biases ----
    for (int i = tid; i < 1024; i += 256) {
        int k = i & 7, b = (i >> 3) & 15, t = (i >> 7) & 1, wv = i >> 8;
        uX[i] = (k < 6)
            ? f2bf(x[(size_t)(b0 + wv * 16 + b) * 1200 + t * 600 + n * 6 + k])
            : (unsigned short)0;
    }
    for (int i = tid; i < 192; i += 256) { fB[i] = bih[n * 192 + i]; fB[192 + i] = bhh[n * 192 + i]; }
    if (tid < 64) { fB[384 + tid] = b1[n * 64 + tid]; fB[448 + tid] = b2[n * 64 + tid]; fB[512 + tid] = W3[n * 64 + tid]; }
    if (tid == 0) fB[576] = b3[n];
    __syncthreads();

    const float b3v = fB[576];
    const int arow = l & 15;
    const int ch0  = grp * 4;          // channel base within M-tile for this lane

    f32x4 hp[4];
#pragma unroll
    for (int mt = 0; mt < 4; ++mt) hp[mt] = (f32x4){0.f, 0.f, 0.f, 0.f};

#pragma unroll
    for (int t = 0; t < 2; ++t) {
        // ---- gate accumulators, bias-initialized from LDS ----
        f32x4 aR[4], aZ[4], aXN[4], aHN[4];
#pragma unroll
        for (int mt = 0; mt < 4; ++mt) {
            int ch = mt * 16 + ch0;
            f32x4 vih_r = *(const f32x4*)&fB[ch];
            f32x4 vhh_r = *(const f32x4*)&fB[192 + ch];
            f32x4 vih_z = *(const f32x4*)&fB[64 + ch];
            f32x4 vhh_z = *(const f32x4*)&fB[256 + ch];
            aR[mt]  = vih_r + vhh_r;
            aZ[mt]  = vih_z + vhh_z;
            aXN[mt] = *(const f32x4*)&fB[128 + ch];
            aHN[mt] = *(const f32x4*)&fB[320 + ch];
        }
        // ---- gx: A = Wih slab [192][32] (k>=6 zero), B = x (broadcast 16B) ----
        {
            short8 bx = *(const short8*)(sm + OFF_X + w * 512 + t * 256 + bcol * 16);
#pragma unroll
            for (int mt = 0; mt < 4; ++mt) {
                short8 a0 = *(const short8*)(zb + ((0 + mt) * 16 + arow) * 32 + grp * 8);
                short8 a1 = *(const short8*)(zb + ((4 + mt) * 16 + arow) * 32 + grp * 8);
                short8 a2 = *(const short8*)(zb + ((8 + mt) * 16 + arow) * 32 + grp * 8);
                aR[mt]  = __builtin_amdgcn_mfma_f32_16x16x32_bf16(a0, bx, aR[mt], 0, 0, 0);
                aZ[mt]  = __builtin_amdgcn_mfma_f32_16x16x32_bf16(a1, bx, aZ[mt], 0, 0, 0);
                aXN[mt] = __builtin_amdgcn_mfma_f32_16x16x32_bf16(a2, bx, aXN[mt], 0, 0, 0);
            }
        }
        // ---- gh (t=1): A = Whh slab [192][64], B = h from per-wave LDS ----
        if (t == 1) {
            const unsigned short* whh = zb + 6144;
            short8 bh0 = *(const short8*)(sm + OFF_H + w * 2304 + bcol * 144 + grp * 16);
            short8 bh1 = *(const short8*)(sm + OFF_H + w * 2304 + bcol * 144 + grp * 16 + 64);
#pragma unroll
            for (int mt = 0; mt < 4; ++mt) {
                short8 r0 = *(const short8*)(whh + ((0 + mt) * 16 + arow) * 64 + grp * 8);
                short8 r1 = *(const short8*)(whh + ((0 + mt) * 16 + arow) * 64 + 32 + grp * 8);
                aR[mt] = __builtin_amdgcn_mfma_f32_16x16x32_bf16(r0, bh0, aR[mt], 0, 0, 0);
                aR[mt] = __builtin_amdgcn_mfma_f32_16x16x32_bf16(r1, bh1, aR[mt], 0, 0, 0);
                short8 z0 = *(const short8*)(whh + ((4 + mt) * 16 + arow) * 64 + grp * 8);
                short8 z1 = *(const short8*)(whh + ((4 + mt) * 16 + arow) * 64 + 32 + grp * 8);
                aZ[mt] = __builtin_amdgcn_mfma_f32_16x16x32_bf16(z0, bh0, aZ[mt], 0, 0, 0);
                aZ[mt] = __builtin_amdgcn_mfma_f32_16x16x32_bf16(z1, bh1, aZ[mt], 0, 0, 0);
                short8 n0 = *(const short8*)(whh + ((8 + mt) * 16 + arow) * 64 + grp * 8);
                short8 n1 = *(const short8*)(whh + ((8 + mt) * 16 + arow) * 64 + 32 + grp * 8);
                aHN[mt] = __builtin_amdgcn_mfma_f32_16x16x32_bf16(n0, bh0, aHN[mt], 0, 0, 0);
                aHN[mt] = __builtin_amdgcn_mfma_f32_16x16x32_bf16(n1, bh1, aHN[mt], 0, 0, 0);
            }
        }
        // ---- GRU cell (fp32) + write h (t0) and relu(h) to LDS ----
#pragma unroll
        for (int mt = 0; mt < 4; ++mt) {
            f32x4 h2;
#pragma unroll
            for (int r = 0; r < 4; ++r) {
                float rg = sigf(aR[mt][r]);
                float zg = sigf(aZ[mt][r]);
                float nn = tanhfast(aXN[mt][r] + rg * aHN[mt][r]);
                h2[r] = nn + zg * (hp[mt][r] - nn);
            }
            hp[mt] = h2;
            unsigned short a0 = f2bf(fmaxf(h2[0], 0.f)), a1 = f2bf(fmaxf(h2[1], 0.f));
            unsigned short a2 = f2bf(fmaxf(h2[2], 0.f)), a3 = f2bf(fmaxf(h2[3], 0.f));
            uint2 pa; pa.x = (unsigned)a0 | ((unsigned)a1 << 16); pa.y = (unsigned)a2 | ((unsigned)a3 << 16);
            if (t == 0) {
                unsigned short s0 = f2bf(h2[0]), s1 = f2bf(h2[1]), s2 = f2bf(h2[2]), s3 = f2bf(h2[3]);
                uint2 ph; ph.x = (unsigned)s0 | ((unsigned)s1 << 16); ph.y = (unsigned)s2 | ((unsigned)s3 << 16);
                *(uint2*)(sm + OFF_H + w * 2304 + bcol * 144 + mt * 32 + grp * 8) = ph;
            }
            *(uint2*)(sm + OFF_ACT + w * 2304 + bcol * 144 + mt * 32 + grp * 8) = pa;
        }
        // ---- MLP layer 1 (reads ACT, writes M1 back into same buffer) ----
        {
            const unsigned short* w1 = zb + 18432;
            short8 ba0 = *(const short8*)(sm + OFF_ACT + w * 2304 + bcol * 144 + grp * 16);
            short8 ba1 = *(const short8*)(sm + OFF_ACT + w * 2304 + bcol * 144 + grp * 16 + 64);
            f32x4 aM[4];
#pragma unroll
            for (int mt = 0; mt < 4; ++mt) {
                aM[mt] = *(const f32x4*)&fB[384 + mt * 16 + ch0];
                short8 a0 = *(const short8*)(w1 + (mt * 16 + arow) * 64 + grp * 8);
                short8 a1 = *(const short8*)(w1 + (mt * 16 + arow) * 64 + 32 + grp * 8);
                aM[mt] = __builtin_amdgcn_mfma_f32_16x16x32_bf16(a0, ba0, aM[mt], 0, 0, 0);
                aM[mt] = __builtin_amdgcn_mfma_f32_16x16x32_bf16(a1, ba1, aM[mt], 0, 0, 0);
            }
#pragma unroll
            for (int mt = 0; mt < 4; ++mt) {
                unsigned short m0 = f2bf(fmaxf(aM[mt][0], 0.f)), m1 = f2bf(fmaxf(aM[mt][1], 0.f));
                unsigned short m2 = f2bf(fmaxf(aM[mt][2], 0.f)), m3 = f2bf(fmaxf(aM[mt][3], 0.f));
                uint2 pm; pm.x = (unsigned)m0 | ((unsigned)m1 << 16); pm.y = (unsigned)m2 | ((unsigned)m3 << 16);
                *(uint2*)(sm + OFF_ACT + w * 2304 + bcol * 144 + mt * 32 + grp * 8) = pm;
            }
        }
        // ---- MLP layer 2 + head ----
        {
            const unsigned short* w2 = zb + 22528;
            short8 bm0 = *(const short8*)(sm + OFF_ACT + w * 2304 + bcol * 144 + grp * 16);
            short8 bm1 = *(const short8*)(sm + OFF_ACT + w * 2304 + bcol * 144 + grp * 16 + 64);
            f32x4 aM2[4];
#pragma unroll
            for (int mt = 0; mt < 4; ++mt) {
                aM2[mt] = *(const f32x4*)&fB[448 + mt * 16 + ch0];
                short8 a0 = *(const short8*)(w2 + (mt * 16 + arow) * 64 + grp * 8);
                short8 a1 = *(const short8*)(w2 + (mt * 16 + arow) * 64 + 32 + grp * 8);
                aM2[mt] = __builtin_amdgcn_mfma_f32_16x16x32_bf16(a0, bm0, aM2[mt], 0, 0, 0);
                aM2[mt] = __builtin_amdgcn_mfma_f32_16x16x32_bf16(a1, bm1, aM2[mt], 0, 0, 0);
            }
            float part = 0.f;
#pragma unroll
            for (int mt = 0; mt < 4; ++mt) {
                int ch = mt * 16 + ch0;
#pragma unroll
                for (int r = 0; r < 4; ++r)
                    part += fB[512 + ch + r] * fmaxf(aM2[mt][r], 0.f);
            }
            part += __shfl_xor(part, 16, 64);
            part += __shfl_xor(part, 32, 64);
            float val = 3.f * (sigf(part + b3v) - 0.5f);
            if (l < 16)
                p_flat[n * 4096 + (b0 + w * 16 + bcol) * 2 + t] = val;   // (n,b,t)-major
        }
    }
}

// ---------------------------------------------------------------------------
// Critic + p-last gather (unchanged): grid 512, block 256, wave per batch row.
// ---------------------------------------------------------------------------
__global__ __launch_bounds__(256, 2)
void critic_kernel(const float* __restrict__ x, const float* __restrict__ p_flat,
                   const float* __restrict__ lmW1, const float* __restrict__ lmb1,
                   const float* __restrict__ lmW2, const float* __restrict__ lmb2,
                   const float* __restrict__ lmW3, const float* __restrict__ lmb3,
                   const float* __restrict__ scWih, const float* __restrict__ scWhh,
                   const float* __restrict__ scbih, const float* __restrict__ scbhh,
                   const float* __restrict__ scW1, const float* __restrict__ scb1,
                   const float* __restrict__ scW2, const float* __restrict__ scb2,
                   const float* __restrict__ scW3, const float* __restrict__ scb3,
                   float* __restrict__ out)
{
    __shared__ float sxi[4][72];
    __shared__ float shh[4][68];
    __shared__ float sab[4][68];
    __shared__ float sc1[4][68];
    __shared__ float sf1[4][132];

    const int tid = threadIdx.x;
    const int wid = tid >> 6;
    const int lane = tid & 63;
    const int b = blockIdx.x * 4 + wid;

    for (int idx = lane; idx < 72; idx += 64) {
        int t = idx / 36, c = idx - t * 36;
        float v = 0.f;
        if (c < 35) {
            int g = c / 7, e = c - g * 7;
            int z = (g == 0) ? 99 : (g == 1) ? 89 : (g == 4) ? 98 : -1;
            if (z >= 0)
                v = (e < 6) ? x[((size_t)b * 2 + t) * 600 + z * 6 + e]
                            : p_flat[b * 200 + t * 100 + z];
        }
        sxi[wid][idx] = v;
    }
    __syncthreads();

    float cg00 = scbih[lane], cg01 = scbih[lane + 64], cg02 = scbih[lane + 128];
    float cg10 = cg00, cg11 = cg01, cg12 = cg02;
    for (int c = 0; c < 35; ++c) {
        float w0 = scWih[lane * 35 + c];
        float w1 = scWih[(lane + 64) * 35 + c];
        float w2 = scWih[(lane + 128) * 35 + c];
        float x0 = sxi[wid][c], x1 = sxi[wid][36 + c];
        cg00 += w0 * x0; cg01 += w1 * x0; cg02 += w2 * x0;
        cg10 += w0 * x1; cg11 += w1 * x1; cg12 += w2 * x1;
    }
    const float bhr = scbhh[lane], bhz = scbhh[lane + 64], bhn = scbhh[lane + 128];
    float r  = 1.f / (1.f + expf(-(cg00 + bhr)));
    float zg = 1.f / (1.f + expf(-(cg01 + bhz)));
    float nn = tanhf(cg02 + r * bhn);
    float hj = (1.f - zg) * nn;
    shh[wid][lane] = hj;
    __syncthreads();
    float ghr = bhr, ghz = bhz, ghn = bhn;
    for (int kc = 0; kc < 16; ++kc) {
        float4 wr = *(const float4*)&scWhh[lane * 64 + kc * 4];
        float4 wzv = *(const float4*)&scWhh[(lane + 64) * 64 + kc * 4];
        float4 wn = *(const float4*)&scWhh[(lane + 128) * 64 + kc * 4];
        float4 hv = *(const float4*)&shh[wid][kc * 4];
        ghr += wr.x * hv.x + wr.y * hv.y + wr.z * hv.z + wr.w * hv.w;
        ghz += wzv.x * hv.x + wzv.y * hv.y + wzv.z * hv.z + wzv.w * hv.w;
        ghn += wn.x * hv.x + wn.y * hv.y + wn.z * hv.z + wn.w * hv.w;
    }
    r  = 1.f / (1.f + expf(-(cg10 + ghr)));
    zg = 1.f / (1.f + expf(-(cg11 + ghz)));
    nn = tanhf(cg12 + r * ghn);
    hj = (1.f - zg) * nn + zg * hj;
    sab[wid][lane] = fmaxf(hj, 0.f);
    __syncthreads();
    float acc = scb1[lane];
    for (int kc = 0; kc < 16; ++kc) {
        float4 wv = *(const float4*)&scW1[lane * 64 + kc * 4];
        float4 av = *(const float4*)&sab[wid][kc * 4];
        acc += wv.x * av.x + wv.y * av.y + wv.z * av.z + wv.w * av.w;
    }
    sc1[wid][lane] = fmaxf(acc, 0.f);
    __syncthreads();
    float acc2 = scb2[lane];
    for (int kc = 0; kc < 16; ++kc) {
        float4 wv = *(const float4*)&scW2[lane * 64 + kc * 4];
        float4 av = *(const float4*)&sc1[wid][kc * 4];
        acc2 += wv.x * av.x + wv.y * av.y + wv.z * av.z + wv.w * av.w;
    }
    float qpart = scW3[lane] * fmaxf(acc2, 0.f);
    float f1a = lmb1[lane], f1c = lmb1[lane + 64];
    for (int c = 0; c < 35; ++c) {
        float xv = sxi[wid][36 + c];
        f1a += lmW1[lane * 35 + c] * xv;
        f1c += lmW1[(lane + 64) * 35 + c] * xv;
    }
    sf1[wid][lane] = fmaxf(f1a, 0.f);
    sf1[wid][lane + 64] = fmaxf(f1c, 0.f);
    __syncthreads();
    float f2a = lmb2[lane], f2c = lmb2[lane + 64];
    for (int kc = 0; kc < 32; ++kc) {
        float4 fv = *(const float4*)&sf1[wid][kc * 4];
        float4 wa = *(const float4*)&lmW2[lane * 128 + kc * 4];
        float4 wc = *(const float4*)&lmW2[(lane + 64) * 128 + kc * 4];
        f2a += wa.x * fv.x + wa.y * fv.y + wa.z * fv.z + wa.w * fv.w;
        f2c += wc.x * fv.x + wc.y * fv.y + wc.z * fv.z + wc.w * fv.w;
    }
    float fpart = lmW3[lane] * fmaxf(f2a, 0.f) + lmW3[lane + 64] * fmaxf(f2c, 0.f);

    float tot = qpart + fpart;
    for (int m = 32; m > 0; m >>= 1) tot += __shfl_xor(tot, m, 64);
    if (lane == 0) out[204800 + b] = tot + scb3[0] + lmb3[0];

    for (int l2 = lane; l2 < 100; l2 += 64)
        out[b * 100 + l2] = p_flat[b * 200 + 100 + l2];
}

extern "C" void kernel_launch(void* const* d_in, const int* in_sizes, int n_in,
                              void* d_out, int out_size, void* d_ws, size_t ws_size,
                              hipStream_t stream) {
    const float* x     = (const float*)d_in[0];
    const float* aWih  = (const float*)d_in[1];
    const float* aWhh  = (const float*)d_in[2];
    const float* abih  = (const float*)d_in[3];
    const float* abhh  = (const float*)d_in[4];
    const float* aW1   = (const float*)d_in[5];
    const float* ab1   = (const float*)d_in[6];
    const float* aW2   = (const float*)d_in[7];
    const float* ab2   = (const float*)d_in[8];
    const float* aW3   = (const float*)d_in[9];
    const float* ab3   = (const float*)d_in[10];
    const float* lmW1  = (const float*)d_in[11];
    const float* lmb1  = (const float*)d_in[12];
    const float* lmW2  = (const float*)d_in[13];
    const float* lmb2  = (const float*)d_in[14];
    const float* lmW3  = (const float*)d_in[15];
    const float* lmb3  = (const float*)d_in[16];
    const float* scWih = (const float*)d_in[17];
    const float* scWhh = (const float*)d_in[18];
    const float* scbih = (const float*)d_in[19];
    const float* scbhh = (const float*)d_in[20];
    const float* scW1  = (const float*)d_in[21];
    const float* scb1  = (const float*)d_in[22];
    const float* scW2  = (const float*)d_in[23];
    const float* scb2  = (const float*)d_in[24];
    const float* scW3  = (const float*)d_in[25];
    const float* scb3  = (const float*)d_in[26];
    float* out = (float*)d_out;
    float* p_flat = (float*)d_ws;                                    // 1.6 MB
    unsigned short* wz = (unsigned short*)((char*)d_ws + WS_W_OFF_BYTES);  // 5.3 MB

    hipFuncSetAttribute((const void*)actor_kernel,
                        hipFuncAttributeMaxDynamicSharedMemorySize, LDS_TOTAL);

    convert_kernel<<<dim3((100 * ZW + 255) / 256), 256, 0, stream>>>(
        aWih, aWhh, aW1, aW2, wz);

    actor_kernel<<<dim3(32, 100), 256, LDS_TOTAL, stream>>>(
        x, wz, abih, abhh, ab1, ab2, aW3, ab3, p_flat);

    critic_kernel<<<dim3(512), 256, 0, stream>>>(
        x, p_flat, lmW1, lmb1, lmW2, lmb2, lmW3, lmb3,
        scWih, scWhh, scbih, scbhh, scW1, scb1, scW2, scb2, scW3, scb3, out);
}